// Round 1
// baseline (369.362 us; speedup 1.0000x reference)
//
#include <hip/hip_runtime.h>
#include <cstdint>
#include <cstddef>

#define CIN   128
#define COUT  256
#define HW    64
#define NSP   4096      // 64*64 spatial
#define KTOT  1152      // CIN*9
#define BATCH 32
#define PDROP 0.2f
#define LDT   40        // LDS row stride in bf16 elems: 32 data + 8 pad (16B-aligned rows)

__device__ __forceinline__ unsigned short f2bf(float f) {
    unsigned int u = __builtin_bit_cast(unsigned int, f);
    u += 0x7fffu + ((u >> 16) & 1u);   // round-to-nearest-even
    return (unsigned short)(u >> 16);
}

// Per-sample masked bf16 weights, transposed to tap-major:
// wt[b][o][r*128 + i] = bf16( weight[o][i][r] * (u_w[b][o][i][r] > p) ),  r = ky*3+kx
__global__ __launch_bounds__(128) void mask_weights(
        const float* __restrict__ weight, const float* __restrict__ u_w,
        unsigned short* __restrict__ wt)
{
    const int bo = blockIdx.x;                 // b*COUT + o
    const int o  = bo & (COUT - 1);
    const int i  = threadIdx.x;                // 0..127 (channel)
    const float* wsrc = weight + (size_t)o  * KTOT + (size_t)i * 9;
    const float* usrc = u_w    + (size_t)bo * KTOT + (size_t)i * 9;
    unsigned short* dst = wt + (size_t)bo * KTOT + i;
    #pragma unroll
    for (int r = 0; r < 9; ++r) {
        float v = (usrc[r] > PDROP) ? wsrc[r] : 0.f;
        dst[r * CIN] = f2bf(v);                // coalesced 128-wide u16 stores per r
    }
}

// Implicit-GEMM conv: per sample, C[o][p] = sum_k Weff[o][k] * Xcol[k][p]
// k = r*128 + i (tap-major). BM=BN=128, BK=32 (one MFMA k-step). 4 waves, wave=64x64.
template<bool USE_WS>
__global__ __launch_bounds__(256) void conv_mfma(
        const float* __restrict__ x, const float* __restrict__ weight,
        const float* __restrict__ bias, const float* __restrict__ u_w,
        const float* __restrict__ u_b, const unsigned short* __restrict__ wt,
        float* __restrict__ out)
{
    using frag  = __attribute__((ext_vector_type(8))) short;   // 8 bf16
    using f32x4 = __attribute__((ext_vector_type(4))) float;

    __shared__ unsigned short As[128 * LDT];   // [o_local][k]   10240 B
    __shared__ unsigned short Bs[128 * LDT];   // [p_local][k]   10240 B

    const int tid  = threadIdx.x;
    const int lane = tid & 63;
    const int q    = lane >> 4;        // quad 0..3
    const int l15  = lane & 15;
    const int wv   = tid >> 6;         // wave 0..3
    const int wm   = (wv >> 1) * 64;   // wave tile offsets in block tile
    const int wn   = (wv & 1) * 64;

    const int b  = blockIdx.z;
    const int m0 = blockIdx.y * 128;   // output-channel base
    const int n0 = blockIdx.x * 128;   // spatial base

    // A staging map: thread -> (row arow, 16 k at acol)
    const int arow = tid >> 1;
    const int acol = (tid & 1) * 16;
    // B staging map: thread -> (p col pn, 16 k at kh)
    const int pn = tid & 127;
    const int kh = (tid >> 7) * 16;
    const int p  = n0 + pn;
    const int ph = p >> 6;
    const int pw = p & 63;

    const float* xb = x + (size_t)b * CIN * NSP;

    f32x4 acc[4][4];
    #pragma unroll
    for (int i = 0; i < 4; ++i)
        #pragma unroll
        for (int j = 0; j < 4; ++j)
            acc[i][j] = (f32x4){0.f, 0.f, 0.f, 0.f};

    const int a_rd = (wm + l15) * LDT + q * 8;
    const int b_rd = (wn + l15) * LDT + q * 8;

    for (int s = 0; s < 36; ++s) {
        const int r  = s >> 2;           // tap index 0..8 (wave-uniform)
        const int i0 = (s & 3) * 32;     // channel base of this K-step
        const int k0 = s * 32;

        // ---- global loads for A tile (into regs; overlaps prev MFMA)
        uint4 av0, av1;
        float aw[16], au[16];
        if (USE_WS) {
            const uint4* src = reinterpret_cast<const uint4*>(
                wt + ((size_t)(b * COUT + m0 + arow)) * KTOT + k0 + acol);
            av0 = src[0];
            av1 = src[1];
        } else {
            const float* wsrc = weight + (size_t)(m0 + arow) * KTOT;
            const float* usrc = u_w + (size_t)(b * COUT + m0 + arow) * KTOT;
            #pragma unroll
            for (int ii = 0; ii < 16; ++ii) {
                const int kk = (i0 + acol + ii) * 9 + r;   // natural OIHW index
                aw[ii] = wsrc[kk];
                au[ii] = usrc[kk];
            }
        }

        // ---- global loads for B tile (implicit im2col, uniform tap per step)
        const int hh = ph + (r / 3) - 1;
        const int ww = pw + (r % 3) - 1;
        float bx[16];
        #pragma unroll
        for (int j = 0; j < 16; ++j) bx[j] = 0.f;
        const bool valid = ((unsigned)hh < 64u) && ((unsigned)ww < 64u);
        if (valid) {
            const float* xsrc = xb + (size_t)(i0 + kh) * NSP + hh * HW + ww;
            #pragma unroll
            for (int j = 0; j < 16; ++j) bx[j] = xsrc[(size_t)j * NSP];
        }

        __syncthreads();   // prior iteration's frag reads complete

        // ---- LDS writes
        if (USE_WS) {
            uint4* d = reinterpret_cast<uint4*>(&As[arow * LDT + acol]);
            d[0] = av0; d[1] = av1;
        } else {
            union { unsigned short u16[16]; uint4 v[2]; } t;
            #pragma unroll
            for (int ii = 0; ii < 16; ++ii)
                t.u16[ii] = f2bf((au[ii] > PDROP) ? aw[ii] : 0.f);
            uint4* d = reinterpret_cast<uint4*>(&As[arow * LDT + acol]);
            d[0] = t.v[0]; d[1] = t.v[1];
        }
        {
            union { unsigned short u16[16]; uint4 v[2]; } t;
            #pragma unroll
            for (int j = 0; j < 16; ++j) t.u16[j] = f2bf(bx[j]);
            uint4* d = reinterpret_cast<uint4*>(&Bs[pn * LDT + kh]);
            d[0] = t.v[0]; d[1] = t.v[1];
        }

        __syncthreads();

        // ---- fragments + MFMA
        // A-frag: lane holds A[m=l15][k=q*8+j]; B-frag: B[k=q*8+j][n=l15] from Bs[n][k]
        frag af[4], bfr[4];
        #pragma unroll
        for (int mi = 0; mi < 4; ++mi)
            af[mi] = *reinterpret_cast<const frag*>(&As[a_rd + mi * 16 * LDT]);
        #pragma unroll
        for (int ni = 0; ni < 4; ++ni)
            bfr[ni] = *reinterpret_cast<const frag*>(&Bs[b_rd + ni * 16 * LDT]);
        #pragma unroll
        for (int mi = 0; mi < 4; ++mi)
            #pragma unroll
            for (int ni = 0; ni < 4; ++ni)
                acc[mi][ni] = __builtin_amdgcn_mfma_f32_16x16x32_bf16(
                    af[mi], bfr[ni], acc[mi][ni], 0, 0, 0);
    }

    // ---- epilogue: D row=(q*4+reg), col=l15 ; add dropped-out bias
    float bv[4][4];
    #pragma unroll
    for (int mi = 0; mi < 4; ++mi)
        #pragma unroll
        for (int rg = 0; rg < 4; ++rg) {
            const int o = m0 + wm + mi * 16 + q * 4 + rg;
            bv[mi][rg] = (u_b[b * COUT + o] > PDROP) ? bias[o] : 0.f;
        }
    float* ob = out + (size_t)b * COUT * NSP;
    #pragma unroll
    for (int mi = 0; mi < 4; ++mi) {
        #pragma unroll
        for (int rg = 0; rg < 4; ++rg) {
            const int o = m0 + wm + mi * 16 + q * 4 + rg;
            float* orow = ob + (size_t)o * NSP + n0 + wn + l15;
            #pragma unroll
            for (int ni = 0; ni < 4; ++ni)
                orow[ni * 16] = acc[mi][ni][rg] + bv[mi][rg];
        }
    }
}

extern "C" void kernel_launch(void* const* d_in, const int* in_sizes, int n_in,
                              void* d_out, int out_size, void* d_ws, size_t ws_size,
                              hipStream_t stream)
{
    const float* x      = (const float*)d_in[0];
    const float* weight = (const float*)d_in[1];
    const float* bias   = (const float*)d_in[2];
    const float* u_w    = (const float*)d_in[3];
    const float* u_b    = (const float*)d_in[4];
    float* out = (float*)d_out;

    const size_t wt_bytes = (size_t)BATCH * COUT * KTOT * sizeof(unsigned short); // 18.9 MB
    dim3 grid(NSP / 128, COUT / 128, BATCH);   // 32 x 2 x 32 = 2048 blocks

    if (ws_size >= wt_bytes) {
        unsigned short* wtp = (unsigned short*)d_ws;
        mask_weights<<<BATCH * COUT, 128, 0, stream>>>(weight, u_w, wtp);
        conv_mfma<true><<<grid, 256, 0, stream>>>(x, weight, bias, u_w, u_b, wtp, out);
    } else {
        conv_mfma<false><<<grid, 256, 0, stream>>>(x, weight, bias, u_w, u_b, nullptr, out);
    }
}